// Round 4
// baseline (509.834 us; speedup 1.0000x reference)
//
#include <hip/hip_runtime.h>
#include <hip/hip_bf16.h>
#include <cstdint>
#include <cstddef>

using bf16 = __hip_bfloat16;

typedef short s16x8 __attribute__((ext_vector_type(8)));
typedef short s16x4 __attribute__((ext_vector_type(4)));
typedef float f32x4 __attribute__((ext_vector_type(4)));

#define CH 32           // scan chunks
#define CS 64           // steps per chunk (CH*CS = 2048)

// ---- static device scratch (sidesteps unknown ws_size) -------------------
__device__ __align__(16) bf16  g_xb[16384 * 1024];      // 32 MiB: x in bf16
__device__ __align__(16) bf16  g_wb[5 * 1024 * 1024];   // 10 MiB: weights bf16
__device__ __align__(16) bf16  g_og[16384 * 1024];      // 32 MiB: output gate
__device__ float g_cA[CH * 8192];                       // scan carries / seeds
__device__ float g_cB[CH * 8192];

__device__ inline short bfbits(float f) {  // RNE f32 -> bf16 bits
  unsigned x = __float_as_uint(f);
  return (short)((x + 0x7FFFu + ((x >> 16) & 1u)) >> 16);
}
__device__ inline float sigmoidf_(float z) { return 1.0f / (1.0f + __expf(-z)); }

__device__ inline void gload_lds16(const void* g, void* l) {
  __builtin_amdgcn_global_load_lds(
      (const __attribute__((address_space(1))) void*)g,
      (__attribute__((address_space(3))) void*)l, 16, 0, 0);
}

// ---- f32 -> bf16 bulk convert (vec4, grid-stride) ------------------------
__global__ void conv_kernel(const float* __restrict__ src, bf16* __restrict__ dst, int n4) {
  int i = blockIdx.x * blockDim.x + threadIdx.x;
  const int stride = gridDim.x * blockDim.x;
  for (; i < n4; i += stride) {
    f32x4 v = ((const f32x4*)src)[i];
    s16x4 w;
    w[0] = bfbits(v[0]); w[1] = bfbits(v[1]);
    w[2] = bfbits(v[2]); w[3] = bfbits(v[3]);
    ((s16x4*)dst)[i] = w;
  }
}

// ===========================================================================
// QUAD GEMM, distance-3 pipeline. TM=256, TN=64, BK=32, 512 thr (8 waves).
//   waves 0-3: {wr, wog} -> r, og.  waves 4-7: {wi, wig} -> xi.
//   4 LDS buffers (4 x (A16K + B16K) = 128 KB). Per tile per wave: 4
//   global_load_lds. Main loop: stage(t+3); compute(t); s_waitcnt vmcnt(8)
//   (tile t+1 resident, tiles t+2/t+3 stay IN FLIGHT across the barrier);
//   s_barrier. Never vmcnt(0) until the tail (T4).
//   Hazard: stage(t+3) overwrites buf[(t-1)&3]; its readers' ds_reads all
//   completed before barrier(t-1) (reads are consumed by MFMAs pre-barrier).
//   Swizzle (64B rows = 4 chunks): LDS slot (row,c) holds global chunk
//   c ^ (row&3); applied on the pre-swizzled global source (LDS dest linear
//   for global_load_lds) and on the ds_read chunk.
//   Grid is N-fastest (16,64): 16 consecutive blocks share one A-tile; each
//   XCD (round-robin %8) sees only n-tiles {x, x+8} -> B set / XCD = 1 MB,
//   resident in L2.
//   K order: k0 = t*32 ascending == previous rounds -> bitwise-identical.
// ===========================================================================
__global__ __launch_bounds__(512, 2) void gemm_quad(
    const bf16* __restrict__ A,
    const bf16* __restrict__ B0, const bf16* __restrict__ B1,
    const bf16* __restrict__ B2, const bf16* __restrict__ B3,
    const float* __restrict__ bias_r, const float* __restrict__ bias_og,
    const float* __restrict__ bias_ig,
    float* __restrict__ Cr, bf16* __restrict__ Cog, bf16* __restrict__ Cxi,
    int M, int N, int K)
{
  __shared__ bf16 As[4][256 * 32];      // 64 KB
  __shared__ bf16 Bs[4][4][64 * 32];    // 64 KB

  const int tid  = threadIdx.x;
  const int wave = tid >> 6;            // 0..7
  const int lane = tid & 63;
  const int n0 = blockIdx.x * 64;       // N-fastest grid
  const int m0 = blockIdx.y * 256;

  // ---- staging: 1 instr = 64 lanes x 16B = 16 rows x 4 chunks ------------
  const int srow16 = lane >> 2;                               // 0..15
  const int schk   = ((lane & 3) ^ ((lane >> 2) & 3)) << 3;   // pre-swizzled src chunk
  const bf16* Bm = (wave < 2) ? B0 : (wave < 4) ? B1 : (wave < 6) ? B2 : B3;
  const bf16* pAs = A  + (size_t)(m0 + wave * 32 + srow16) * K + schk;
  const bf16* pBs = Bm + (size_t)(n0 + (wave & 1) * 32 + srow16) * K + schk;
  const size_t krow16 = (size_t)16 * K;

  // ---- ds_read offsets (swizzled; row&3 == lane15&3 for all frags) -------
  const int lane15 = lane & 15;
  const int csel   = lane >> 4;         // 0..3 (8-elem chunk)
  const int o = lane15 * 32 + ((csel ^ (lane15 & 3)) << 3);
  const int wmA = (wave & 3) * 2048;    // (wave&3)*64 rows * 32 cols
  const int mlo = (wave >> 2) * 2;      // 0 (waves 0-3) or 2 (waves 4-7)

  f32x4 accP[4][4] = {};   // mat mlo   (r  or lin)
  f32x4 accQ[4][4] = {};   // mat mlo+1 (og or gate)

  auto stage = [&](int b, size_t koff) {
    bf16* as = &As[b][wave * 1024];
    bf16* bs = &Bs[b][wave >> 1][(wave & 1) * 1024];
    gload_lds16(pAs + koff,          (void*)as);
    gload_lds16(pAs + krow16 + koff, (void*)(as + 512));
    gload_lds16(pBs + koff,          (void*)bs);
    gload_lds16(pBs + krow16 + koff, (void*)(bs + 512));
  };

  auto compute = [&](int c) {
    const bf16* aB  = &As[c][wmA + o];
    const bf16* b0B = &Bs[c][mlo][o];
    const bf16* b1B = &Bs[c][mlo + 1][o];
    s16x8 af[4], f0[4], f1[4];
    #pragma unroll
    for (int i = 0; i < 4; ++i) af[i] = *(const s16x8*)(aB + i * 512);
    #pragma unroll
    for (int j = 0; j < 4; ++j) {
      f0[j] = *(const s16x8*)(b0B + j * 512);
      f1[j] = *(const s16x8*)(b1B + j * 512);
    }
    __builtin_amdgcn_s_setprio(1);
    #pragma unroll
    for (int i = 0; i < 4; ++i)
      #pragma unroll
      for (int j = 0; j < 4; ++j) {
        accP[i][j] = __builtin_amdgcn_mfma_f32_16x16x32_bf16(af[i], f0[j], accP[i][j], 0, 0, 0);
        accQ[i][j] = __builtin_amdgcn_mfma_f32_16x16x32_bf16(af[i], f1[j], accQ[i][j], 0, 0, 0);
      }
    __builtin_amdgcn_s_setprio(0);
  };

  // prologue: tiles 0,1,2 in flight (12 loads); wait oldest 4 = tile 0
  stage(0, 0);
  stage(1, 32);
  stage(2, 64);
  asm volatile("s_waitcnt vmcnt(8)" ::: "memory");
  __builtin_amdgcn_s_barrier();
  __builtin_amdgcn_sched_barrier(0);

  for (int t = 0; t < 29; ++t) {
    stage((t + 3) & 3, (size_t)(t + 3) * 32);
    __builtin_amdgcn_sched_barrier(0);
    compute(t & 3);
    // 12 outstanding (t+1,t+2,t+3); tile t+1 = oldest 4 must land
    asm volatile("s_waitcnt vmcnt(8)" ::: "memory");
    __builtin_amdgcn_s_barrier();
    __builtin_amdgcn_sched_barrier(0);
  }
  // t=29: tiles 30,31 in flight (8); need tile 30
  compute(29 & 3);
  asm volatile("s_waitcnt vmcnt(4)" ::: "memory");
  __builtin_amdgcn_s_barrier();
  __builtin_amdgcn_sched_barrier(0);
  // t=30: tile 31 in flight (4); need tile 31
  compute(30 & 3);
  asm volatile("s_waitcnt vmcnt(0)" ::: "memory");
  __builtin_amdgcn_s_barrier();
  __builtin_amdgcn_sched_barrier(0);
  // t=31
  compute(31 & 3);

  // ---- epilogue ----
  const int rq = (lane >> 4) * 4;
  const int cl = lane & 15;
  const int wr0 = m0 + (wave & 3) * 64;
  if (wave < 4) {
    #pragma unroll
    for (int j = 0; j < 4; ++j) {
      const int gc = n0 + j * 16 + cl;
      const float bR = bias_r[gc];
      const float bO = bias_og[gc];
      #pragma unroll
      for (int i = 0; i < 4; ++i) {
        const int gr = wr0 + i * 16 + rq;
        #pragma unroll
        for (int rr = 0; rr < 4; ++rr) {
          const size_t idx = (size_t)(gr + rr) * N + gc;
          Cr[idx]  = sigmoidf_(accP[i][j][rr] + bR);
          Cog[idx] = __float2bfloat16(sigmoidf_(accQ[i][j][rr] + bO));
        }
      }
    }
  } else {
    #pragma unroll
    for (int j = 0; j < 4; ++j) {
      const int gc = n0 + j * 16 + cl;
      const float bG = bias_ig[gc];
      #pragma unroll
      for (int i = 0; i < 4; ++i) {
        const int gr = wr0 + i * 16 + rq;
        #pragma unroll
        for (int rr = 0; rr < 4; ++rr) {
          const size_t idx = (size_t)(gr + rr) * N + gc;
          Cxi[idx] = __float2bfloat16(accP[i][j][rr] * sigmoidf_(accQ[i][j][rr] + bG));
        }
      }
    }
  }
}

// ===========================================================================
// gemm_single: y = z @ wo^T. TM=256, TN=128, BK=32, 512 thr, wave grid 4Mx2N.
// Distance-3 pipeline, 4 buffers (4 x (A16K + B8K) = 96 KB), 3 loads/wave
// per tile -> counted vmcnt(6), tail 3 -> 0. N-fastest grid (8,64).
// ===========================================================================
__global__ __launch_bounds__(512, 2) void gemm_single(
    const bf16* __restrict__ A, const bf16* __restrict__ Bw,
    float* __restrict__ C, int M, int N, int K)
{
  __shared__ bf16 As[4][256 * 32];   // 64 KB
  __shared__ bf16 Bs[4][128 * 32];   // 32 KB

  const int tid  = threadIdx.x;
  const int wave = tid >> 6;
  const int lane = tid & 63;
  const int n0 = blockIdx.x * 128;   // N-fastest grid
  const int m0 = blockIdx.y * 256;
  const int wm = (wave >> 1) * 64;
  const int wn = (wave & 1) * 64;

  const int srow16 = lane >> 2;
  const int schk   = ((lane & 3) ^ ((lane >> 2) & 3)) << 3;
  const bf16* pAs = A  + (size_t)(m0 + wave * 32 + srow16) * K + schk;
  const bf16* pBs = Bw + (size_t)(n0 + wave * 16 + srow16) * K + schk;
  const size_t krow16 = (size_t)16 * K;

  const int lane15 = lane & 15;
  const int csel   = lane >> 4;
  const int o = lane15 * 32 + ((csel ^ (lane15 & 3)) << 3);

  f32x4 acc[4][4] = {};

  auto stage = [&](int b, size_t koff) {
    bf16* as = &As[b][wave * 1024];
    gload_lds16(pAs + koff,          (void*)as);
    gload_lds16(pAs + krow16 + koff, (void*)(as + 512));
    gload_lds16(pBs + koff,          (void*)&Bs[b][wave * 512]);
  };

  auto compute = [&](int c) {
    const bf16* aB = &As[c][wm * 32 + o];
    const bf16* bB = &Bs[c][wn * 32 + o];
    s16x8 af[4], bfr[4];
    #pragma unroll
    for (int i = 0; i < 4; ++i) af[i] = *(const s16x8*)(aB + i * 512);
    #pragma unroll
    for (int j = 0; j < 4; ++j) bfr[j] = *(const s16x8*)(bB + j * 512);
    __builtin_amdgcn_s_setprio(1);
    #pragma unroll
    for (int i = 0; i < 4; ++i)
      #pragma unroll
      for (int j = 0; j < 4; ++j)
        acc[i][j] = __builtin_amdgcn_mfma_f32_16x16x32_bf16(af[i], bfr[j], acc[i][j], 0, 0, 0);
    __builtin_amdgcn_s_setprio(0);
  };

  stage(0, 0);
  stage(1, 32);
  stage(2, 64);
  asm volatile("s_waitcnt vmcnt(6)" ::: "memory");
  __builtin_amdgcn_s_barrier();
  __builtin_amdgcn_sched_barrier(0);

  for (int t = 0; t < 29; ++t) {
    stage((t + 3) & 3, (size_t)(t + 3) * 32);
    __builtin_amdgcn_sched_barrier(0);
    compute(t & 3);
    asm volatile("s_waitcnt vmcnt(6)" ::: "memory");
    __builtin_amdgcn_s_barrier();
    __builtin_amdgcn_sched_barrier(0);
  }
  compute(29 & 3);
  asm volatile("s_waitcnt vmcnt(3)" ::: "memory");
  __builtin_amdgcn_s_barrier();
  __builtin_amdgcn_sched_barrier(0);
  compute(30 & 3);
  asm volatile("s_waitcnt vmcnt(0)" ::: "memory");
  __builtin_amdgcn_s_barrier();
  __builtin_amdgcn_sched_barrier(0);
  compute(31 & 3);

  const int rq = (lane >> 4) * 4;
  const int cl = lane & 15;
  #pragma unroll
  for (int j = 0; j < 4; ++j) {
    const int gc = n0 + wn + j * 16 + cl;
    #pragma unroll
    for (int i = 0; i < 4; ++i) {
      const int gr = m0 + wm + i * 16 + rq;
      #pragma unroll
      for (int rr = 0; rr < 4; ++rr)
        C[(size_t)(gr + rr) * N + gc] = acc[i][j][rr];
    }
  }
}

// ---- chunked scan --------------------------------------------------------
__global__ __launch_bounds__(256) void scan_p1(
    const float* __restrict__ r, const bf16* __restrict__ xi)
{
  const int bid = blockIdx.x;                 // 0..1023
  const int c   = bid >> 5;                   // chunk
  const int idx = (bid & 31) * 256 + threadIdx.x;  // channel 0..8191
  const int b = idx >> 10, m = idx & 1023;
  const size_t base = ((size_t)b * 2048 + c * CS) * 1024 + m;
  float a = 1.0f, s = 0.0f;
  #pragma unroll 16
  for (int t = 0; t < CS; ++t) {
    const size_t o = base + (size_t)t * 1024;
    const float rv = r[o];
    const float xv = __bfloat162float(xi[o]);
    a *= rv;
    s = fmaf(s, rv, xv);
  }
  g_cA[c * 8192 + idx] = a;
  g_cB[c * 8192 + idx] = s;
}

__global__ __launch_bounds__(256) void scan_p2(
    const float* __restrict__ mem, float* __restrict__ memout)
{
  const int idx = blockIdx.x * 256 + threadIdx.x;  // 0..8191
  float H = mem[idx];
  #pragma unroll
  for (int c = 0; c < CH; ++c) {
    const float a = g_cA[c * 8192 + idx];
    const float s = g_cB[c * 8192 + idx];
    g_cA[c * 8192 + idx] = H;     // seed for chunk c
    H = fmaf(a, H, s);
  }
  memout[idx] = H;
}

__global__ __launch_bounds__(256) void scan_p3(
    const float* __restrict__ r, bf16* xi, const bf16* __restrict__ og)
{
  const int bid = blockIdx.x;
  const int c   = bid >> 5;
  const int idx = (bid & 31) * 256 + threadIdx.x;
  const int b = idx >> 10, m = idx & 1023;
  const size_t base = ((size_t)b * 2048 + c * CS) * 1024 + m;
  float h = g_cA[c * 8192 + idx];
  #pragma unroll 8
  for (int t = 0; t < CS; ++t) {
    const size_t o = base + (size_t)t * 1024;
    const float rv = r[o];
    const float xv = __bfloat162float(xi[o]);
    const float ov = __bfloat162float(og[o]);
    h = fmaf(h, rv, xv);
    xi[o] = __float2bfloat16(h / (1.0f + fabsf(h)) * ov);
  }
}

extern "C" void kernel_launch(void* const* d_in, const int* in_sizes, int n_in,
                              void* d_out, int out_size, void* d_ws, size_t ws_size,
                              hipStream_t stream)
{
  const float* x     = (const float*)d_in[0];
  const float* mem   = (const float*)d_in[1];
  const float* wr_w  = (const float*)d_in[2];
  const float* wr_b  = (const float*)d_in[3];
  const float* wi_w  = (const float*)d_in[4];
  const float* wig_w = (const float*)d_in[5];
  const float* wig_b = (const float*)d_in[6];
  const float* wog_w = (const float*)d_in[7];
  const float* wog_b = (const float*)d_in[8];
  const float* wo_w  = (const float*)d_in[9];
  float* out = (float*)d_out;

  const int M = 16384, N = 1024, K = 1024;
  const size_t MN = (size_t)M * N;

  // ws: [r f32: 64 MiB][xi bf16: 32 MiB]  (96 MiB; proven available)
  float* r  = (float*)d_ws;
  bf16*  xi = (bf16*)((char*)d_ws + MN * 4);

  bf16* xb = nullptr, *wb = nullptr, *og = nullptr;
  hipGetSymbolAddress((void**)&xb, HIP_SYMBOL(g_xb));
  hipGetSymbolAddress((void**)&wb, HIP_SYMBOL(g_wb));
  hipGetSymbolAddress((void**)&og, HIP_SYMBOL(g_og));

  dim3 block(256);

  // 1) convert x and 5 weights to bf16
  conv_kernel<<<dim3(2048), block, 0, stream>>>(x, xb, (int)(MN / 4));
  const int W4 = 1024 * 1024 / 4;
  conv_kernel<<<dim3(256), block, 0, stream>>>(wr_w,  wb + 0 * 1024 * 1024, W4);
  conv_kernel<<<dim3(256), block, 0, stream>>>(wi_w,  wb + 1 * 1024 * 1024, W4);
  conv_kernel<<<dim3(256), block, 0, stream>>>(wig_w, wb + 2 * 1024 * 1024, W4);
  conv_kernel<<<dim3(256), block, 0, stream>>>(wog_w, wb + 3 * 1024 * 1024, W4);
  conv_kernel<<<dim3(256), block, 0, stream>>>(wo_w,  wb + 4 * 1024 * 1024, W4);

  // 2+3) all four projections in one pass (N-fastest grid for L2 locality)
  gemm_quad<<<dim3(16, 64), dim3(512), 0, stream>>>(
      xb,
      wb + 0 * 1024 * 1024,   // wr
      wb + 3 * 1024 * 1024,   // wog
      wb + 1 * 1024 * 1024,   // wi
      wb + 2 * 1024 * 1024,   // wig
      wr_b, wog_b, wig_b,
      r, og, xi, M, N, K);

  // 4) chunked scan; z in-place over xi; mem_out -> out tail (f32)
  scan_p1<<<dim3(1024), block, 0, stream>>>(r, xi);
  scan_p2<<<dim3(32),   block, 0, stream>>>(mem, out + MN);
  scan_p3<<<dim3(1024), block, 0, stream>>>(r, xi, og);

  // 5) y = z @ wo^T
  gemm_single<<<dim3(8, 64), dim3(512), 0, stream>>>(
      xi, wb + 4 * 1024 * 1024, out, M, N, K);
}

// Round 5
// 492.082 us; speedup vs baseline: 1.0361x; 1.0361x over previous
//
#include <hip/hip_runtime.h>
#include <hip/hip_bf16.h>
#include <cstdint>
#include <cstddef>

using bf16 = __hip_bfloat16;

typedef short s16x8 __attribute__((ext_vector_type(8)));
typedef short s16x4 __attribute__((ext_vector_type(4)));
typedef float f32x4 __attribute__((ext_vector_type(4)));

#define CH 32           // scan chunks
#define CS 64           // steps per chunk (CH*CS = 2048)

// ---- static device scratch (sidesteps unknown ws_size) -------------------
__device__ __align__(16) bf16  g_xb[16384 * 1024];      // 32 MiB: x in bf16
__device__ __align__(16) bf16  g_wb[5 * 1024 * 1024];   // 10 MiB: weights bf16
__device__ __align__(16) bf16  g_og[16384 * 1024];      // 32 MiB: output gate
__device__ float g_cA[CH * 8192];                       // scan carries / seeds
__device__ float g_cB[CH * 8192];

__device__ inline short bfbits(float f) {  // RNE f32 -> bf16 bits
  unsigned x = __float_as_uint(f);
  return (short)((x + 0x7FFFu + ((x >> 16) & 1u)) >> 16);
}
__device__ inline float sigmoidf_(float z) { return 1.0f / (1.0f + __expf(-z)); }

__device__ inline void gload_lds16(const void* g, void* l) {
  __builtin_amdgcn_global_load_lds(
      (const __attribute__((address_space(1))) void*)g,
      (__attribute__((address_space(3))) void*)l, 16, 0, 0);
}

// ---- f32 -> bf16 bulk convert (vec4, grid-stride) ------------------------
__global__ void conv_kernel(const float* __restrict__ src, bf16* __restrict__ dst, int n4) {
  int i = blockIdx.x * blockDim.x + threadIdx.x;
  const int stride = gridDim.x * blockDim.x;
  for (; i < n4; i += stride) {
    f32x4 v = ((const f32x4*)src)[i];
    s16x4 w;
    w[0] = bfbits(v[0]); w[1] = bfbits(v[1]);
    w[2] = bfbits(v[2]); w[3] = bfbits(v[3]);
    ((s16x4*)dst)[i] = w;
  }
}

// ===========================================================================
// QUAD GEMM v5: A-only LDS, B direct global->register (L2-resident weights).
//   TM=256, TN=64, BK=64, 512 thr (8 waves as 2M x 4N; each wave computes a
//   128x16 patch for ALL FOUR mats -> B redundancy only x2 across m-rows).
//   A: 3 LDS buffers (3 x 32 KB = 96 KB), distance-2 prefetch; in-loop wait
//   is a COUNTED s_waitcnt vmcnt(12) (= A(t+2) 4 + B(t+1) 8 newest in
//   flight) -> A loads span barriers, never a full drain until the tail.
//   Safety: vmem counter retires in order; the compiler's own wait on the
//   B(t) register loads (issued after A(t+1)) already implies A(t+1) landed.
//   B: 8 x global_load_dwordx4 per wave per step, double-banked registers
//   (bEven/bOdd), compiler-managed waits, no LDS/barrier involvement.
//   Swizzle: R3's verified 8-chunk XOR (c16 ^ (row&7)), 0 conflicts.
//   Grid M-fastest (R4's N-fastest raised FETCH 50% - reverted).
//   K order: t*64 + kk*32 ascending == all prior rounds -> identical math.
// ===========================================================================
__global__ __launch_bounds__(512, 2) void gemm_quad(
    const bf16* __restrict__ A,
    const bf16* __restrict__ B0, const bf16* __restrict__ B1,
    const bf16* __restrict__ B2, const bf16* __restrict__ B3,
    const float* __restrict__ bias_r, const float* __restrict__ bias_og,
    const float* __restrict__ bias_ig,
    float* __restrict__ Cr, bf16* __restrict__ Cog, bf16* __restrict__ Cxi,
    int M, int N, int K)
{
  __shared__ bf16 As[3][256 * 64];      // 96 KB

  const int tid  = threadIdx.x;
  const int wave = tid >> 6;            // 0..7
  const int lane = tid & 63;
  const int m0 = blockIdx.x * 256;      // M-fastest grid
  const int n0 = blockIdx.y * 64;
  const int mrow = wave >> 2;           // 0..1 (128-row half)
  const int ncol = wave & 3;            // 0..3 (16-col slice)

  // ---- A staging: 1 instr = 64 lanes x 16B = 8 rows x 8 chunks -----------
  const int srow8 = lane >> 3;                              // 0..7
  const int schk  = ((lane & 7) ^ ((lane >> 3) & 7)) << 3;  // pre-swizzled src chunk
  const bf16* pAs = A + (size_t)(m0 + wave * 32 + srow8) * K + schk;

  // ---- A ds_read offsets (swizzled) --------------------------------------
  const int lane15 = lane & 15;
  const int csel   = lane >> 4;         // 0..3
  int oA[2];
  #pragma unroll
  for (int kk = 0; kk < 2; ++kk)
    oA[kk] = lane15 * 64 + ((((kk << 2) + csel) ^ (lane15 & 7)) << 3);

  // ---- B per-lane base (element offset into each weight matrix) ----------
  const size_t bOffL = (size_t)(n0 + ncol * 16 + lane15) * K + csel * 8;

  f32x4 acc[4][8] = {};   // [mat][i]; mats: 0=wr 1=wog 2=wi 3=wig

  auto stageA = [&](int b, int t) {
    const size_t koff = (size_t)t * 64;
    bf16* dst = &As[b][wave * 2048];
    gload_lds16(pAs + koff,                   (void*)dst);
    gload_lds16(pAs + koff + (size_t)8  * K,  (void*)(dst + 512));
    gload_lds16(pAs + koff + (size_t)16 * K,  (void*)(dst + 1024));
    gload_lds16(pAs + koff + (size_t)24 * K,  (void*)(dst + 1536));
  };

  auto loadB = [&](s16x8 (&d)[4][2], int t) {
    const size_t kb = bOffL + (size_t)t * 64;
    d[0][0] = *(const s16x8*)(B0 + kb); d[0][1] = *(const s16x8*)(B0 + kb + 32);
    d[1][0] = *(const s16x8*)(B1 + kb); d[1][1] = *(const s16x8*)(B1 + kb + 32);
    d[2][0] = *(const s16x8*)(B2 + kb); d[2][1] = *(const s16x8*)(B2 + kb + 32);
    d[3][0] = *(const s16x8*)(B3 + kb); d[3][1] = *(const s16x8*)(B3 + kb + 32);
  };

  auto compute = [&](int t, const s16x8 (&bq)[4][2]) {
    const bf16* Ab = &As[t % 3][mrow * 8192];
    #pragma unroll
    for (int kk = 0; kk < 2; ++kk) {
      s16x8 af[8];
      const int ob = oA[kk];
      #pragma unroll
      for (int i = 0; i < 8; ++i) af[i] = *(const s16x8*)(Ab + ob + i * 1024);
      __builtin_amdgcn_s_setprio(1);
      #pragma unroll
      for (int i = 0; i < 8; ++i) {
        acc[0][i] = __builtin_amdgcn_mfma_f32_16x16x32_bf16(af[i], bq[0][kk], acc[0][i], 0, 0, 0);
        acc[1][i] = __builtin_amdgcn_mfma_f32_16x16x32_bf16(af[i], bq[1][kk], acc[1][i], 0, 0, 0);
        acc[2][i] = __builtin_amdgcn_mfma_f32_16x16x32_bf16(af[i], bq[2][kk], acc[2][i], 0, 0, 0);
        acc[3][i] = __builtin_amdgcn_mfma_f32_16x16x32_bf16(af[i], bq[3][kk], acc[3][i], 0, 0, 0);
      }
      __builtin_amdgcn_s_setprio(0);
    }
  };

  s16x8 bEven[4][2], bOdd[4][2];

  // prologue: A(0), A(1) staged; B(0) in regs; wait oldest 4 (= A(0))
  stageA(0, 0);
  stageA(1, 1);
  loadB(bEven, 0);
  asm volatile("s_waitcnt vmcnt(12)" ::: "memory");
  __builtin_amdgcn_s_barrier();
  __builtin_amdgcn_sched_barrier(0);

  #pragma unroll 1
  for (int d = 0; d < 7; ++d) {         // t = 0..13
    const int t = 2 * d;
    stageA((t + 2) % 3, t + 2);
    loadB(bOdd, t + 1);
    __builtin_amdgcn_sched_barrier(0);
    compute(t, bEven);
    asm volatile("s_waitcnt vmcnt(12)" ::: "memory");   // A(t+1) resident
    __builtin_amdgcn_s_barrier();
    __builtin_amdgcn_sched_barrier(0);

    stageA((t + 3) % 3, t + 3);
    loadB(bEven, t + 2);
    __builtin_amdgcn_sched_barrier(0);
    compute(t + 1, bOdd);
    asm volatile("s_waitcnt vmcnt(12)" ::: "memory");   // A(t+2) resident
    __builtin_amdgcn_s_barrier();
    __builtin_amdgcn_sched_barrier(0);
  }
  // t = 14: no more A stages; B(15) only
  loadB(bOdd, 15);
  __builtin_amdgcn_sched_barrier(0);
  compute(14, bEven);
  asm volatile("s_waitcnt vmcnt(8)" ::: "memory");      // A(15) resident
  __builtin_amdgcn_s_barrier();
  __builtin_amdgcn_sched_barrier(0);
  // t = 15
  compute(15, bOdd);

  // ---- epilogue: r (f32), og (bf16), xi (bf16) ---------------------------
  const int rq = (lane >> 4) * 4;
  const int cl = lane & 15;
  const int gc = n0 + ncol * 16 + cl;
  const float bR = bias_r[gc];
  const float bO = bias_og[gc];
  const float bG = bias_ig[gc];
  #pragma unroll
  for (int i = 0; i < 8; ++i) {
    const int gr = m0 + mrow * 128 + i * 16 + rq;
    #pragma unroll
    for (int rr = 0; rr < 4; ++rr) {
      const size_t idx = (size_t)(gr + rr) * N + gc;
      Cr[idx]  = sigmoidf_(acc[0][i][rr] + bR);
      Cog[idx] = __float2bfloat16(sigmoidf_(acc[1][i][rr] + bO));
      Cxi[idx] = __float2bfloat16(acc[2][i][rr] * sigmoidf_(acc[3][i][rr] + bG));
    }
  }
}

// ===========================================================================
// gemm_single v5: y = z @ wo^T. Same skeleton: A-only LDS (3 x 32 KB),
// B->regs. TM=256, TN=128, waves 2M x 4N (128x32 each), grid M-fastest
// (64, 8) = 512 blocks = 2 rounds x 16 walls. In-loop vmcnt(8) = A(t+2) 4
// + B(t+1) 4 newest.
// ===========================================================================
__global__ __launch_bounds__(512, 2) void gemm_single(
    const bf16* __restrict__ A, const bf16* __restrict__ Bw,
    float* __restrict__ C, int M, int N, int K)
{
  __shared__ bf16 As[3][256 * 64];   // 96 KB

  const int tid  = threadIdx.x;
  const int wave = tid >> 6;
  const int lane = tid & 63;
  const int m0 = blockIdx.x * 256;   // M-fastest grid
  const int n0 = blockIdx.y * 128;
  const int mrow = wave >> 2;        // 0..1
  const int ncol = wave & 3;         // 0..3 (32-col slice)

  const int srow8 = lane >> 3;
  const int schk  = ((lane & 7) ^ ((lane >> 3) & 7)) << 3;
  const bf16* pAs = A + (size_t)(m0 + wave * 32 + srow8) * K + schk;

  const int lane15 = lane & 15;
  const int csel   = lane >> 4;
  int oA[2];
  #pragma unroll
  for (int kk = 0; kk < 2; ++kk)
    oA[kk] = lane15 * 64 + ((((kk << 2) + csel) ^ (lane15 & 7)) << 3);

  const size_t bOff0 = (size_t)(n0 + ncol * 32 + lane15) * K + csel * 8;
  const size_t bOff1 = bOff0 + (size_t)16 * K;

  f32x4 acc[2][8] = {};   // [j][i]

  auto stageA = [&](int b, int t) {
    const size_t koff = (size_t)t * 64;
    bf16* dst = &As[b][wave * 2048];
    gload_lds16(pAs + koff,                  (void*)dst);
    gload_lds16(pAs + koff + (size_t)8  * K, (void*)(dst + 512));
    gload_lds16(pAs + koff + (size_t)16 * K, (void*)(dst + 1024));
    gload_lds16(pAs + koff + (size_t)24 * K, (void*)(dst + 1536));
  };

  auto loadB = [&](s16x8 (&d)[2][2], int t) {
    const size_t kb = (size_t)t * 64;
    d[0][0] = *(const s16x8*)(Bw + bOff0 + kb); d[0][1] = *(const s16x8*)(Bw + bOff0 + kb + 32);
    d[1][0] = *(const s16x8*)(Bw + bOff1 + kb); d[1][1] = *(const s16x8*)(Bw + bOff1 + kb + 32);
  };

  auto compute = [&](int t, const s16x8 (&bq)[2][2]) {
    const bf16* Ab = &As[t % 3][mrow * 8192];
    #pragma unroll
    for (int kk = 0; kk < 2; ++kk) {
      s16x8 af[8];
      const int ob = oA[kk];
      #pragma unroll
      for (int i = 0; i < 8; ++i) af[i] = *(const s16x8*)(Ab + ob + i * 1024);
      __builtin_amdgcn_s_setprio(1);
      #pragma unroll
      for (int i = 0; i < 8; ++i) {
        acc[0][i] = __builtin_amdgcn_mfma_f32_16x16x32_bf16(af[i], bq[0][kk], acc[0][i], 0, 0, 0);
        acc[1][i] = __builtin_amdgcn_mfma_f32_16x16x32_bf16(af[i], bq[1][kk], acc[1][i], 0, 0, 0);
      }
      __builtin_amdgcn_s_setprio(0);
    }
  };

  s16x8 bEven[2][2], bOdd[2][2];

  stageA(0, 0);
  stageA(1, 1);
  loadB(bEven, 0);
  asm volatile("s_waitcnt vmcnt(8)" ::: "memory");
  __builtin_amdgcn_s_barrier();
  __builtin_amdgcn_sched_barrier(0);

  #pragma unroll 1
  for (int d = 0; d < 7; ++d) {
    const int t = 2 * d;
    stageA((t + 2) % 3, t + 2);
    loadB(bOdd, t + 1);
    __builtin_amdgcn_sched_barrier(0);
    compute(t, bEven);
    asm volatile("s_waitcnt vmcnt(8)" ::: "memory");
    __builtin_amdgcn_s_barrier();
    __builtin_amdgcn_sched_barrier(0);

    stageA((t + 3) % 3, t + 3);
    loadB(bEven, t + 2);
    __builtin_amdgcn_sched_barrier(0);
    compute(t + 1, bOdd);
    asm volatile("s_waitcnt vmcnt(8)" ::: "memory");
    __builtin_amdgcn_s_barrier();
    __builtin_amdgcn_sched_barrier(0);
  }
  loadB(bOdd, 15);
  __builtin_amdgcn_sched_barrier(0);
  compute(14, bEven);
  asm volatile("s_waitcnt vmcnt(4)" ::: "memory");
  __builtin_amdgcn_s_barrier();
  __builtin_amdgcn_sched_barrier(0);
  compute(15, bOdd);

  const int rq = (lane >> 4) * 4;
  const int cl = lane & 15;
  #pragma unroll
  for (int j = 0; j < 2; ++j) {
    const int gc = n0 + ncol * 32 + j * 16 + cl;
    #pragma unroll
    for (int i = 0; i < 8; ++i) {
      const int gr = m0 + mrow * 128 + i * 16 + rq;
      #pragma unroll
      for (int rr = 0; rr < 4; ++rr)
        C[(size_t)(gr + rr) * N + gc] = acc[j][i][rr];
    }
  }
}

// ---- chunked scan --------------------------------------------------------
__global__ __launch_bounds__(256) void scan_p1(
    const float* __restrict__ r, const bf16* __restrict__ xi)
{
  const int bid = blockIdx.x;                 // 0..1023
  const int c   = bid >> 5;                   // chunk
  const int idx = (bid & 31) * 256 + threadIdx.x;  // channel 0..8191
  const int b = idx >> 10, m = idx & 1023;
  const size_t base = ((size_t)b * 2048 + c * CS) * 1024 + m;
  float a = 1.0f, s = 0.0f;
  #pragma unroll 16
  for (int t = 0; t < CS; ++t) {
    const size_t o = base + (size_t)t * 1024;
    const float rv = r[o];
    const float xv = __bfloat162float(xi[o]);
    a *= rv;
    s = fmaf(s, rv, xv);
  }
  g_cA[c * 8192 + idx] = a;
  g_cB[c * 8192 + idx] = s;
}

__global__ __launch_bounds__(256) void scan_p2(
    const float* __restrict__ mem, float* __restrict__ memout)
{
  const int idx = blockIdx.x * 256 + threadIdx.x;  // 0..8191
  float H = mem[idx];
  #pragma unroll
  for (int c = 0; c < CH; ++c) {
    const float a = g_cA[c * 8192 + idx];
    const float s = g_cB[c * 8192 + idx];
    g_cA[c * 8192 + idx] = H;     // seed for chunk c
    H = fmaf(a, H, s);
  }
  memout[idx] = H;
}

__global__ __launch_bounds__(256) void scan_p3(
    const float* __restrict__ r, bf16* xi, const bf16* __restrict__ og)
{
  const int bid = blockIdx.x;
  const int c   = bid >> 5;
  const int idx = (bid & 31) * 256 + threadIdx.x;
  const int b = idx >> 10, m = idx & 1023;
  const size_t base = ((size_t)b * 2048 + c * CS) * 1024 + m;
  float h = g_cA[c * 8192 + idx];
  #pragma unroll 8
  for (int t = 0; t < CS; ++t) {
    const size_t o = base + (size_t)t * 1024;
    const float rv = r[o];
    const float xv = __bfloat162float(xi[o]);
    const float ov = __bfloat162float(og[o]);
    h = fmaf(h, rv, xv);
    xi[o] = __float2bfloat16(h / (1.0f + fabsf(h)) * ov);
  }
}

extern "C" void kernel_launch(void* const* d_in, const int* in_sizes, int n_in,
                              void* d_out, int out_size, void* d_ws, size_t ws_size,
                              hipStream_t stream)
{
  const float* x     = (const float*)d_in[0];
  const float* mem   = (const float*)d_in[1];
  const float* wr_w  = (const float*)d_in[2];
  const float* wr_b  = (const float*)d_in[3];
  const float* wi_w  = (const float*)d_in[4];
  const float* wig_w = (const float*)d_in[5];
  const float* wig_b = (const float*)d_in[6];
  const float* wog_w = (const float*)d_in[7];
  const float* wog_b = (const float*)d_in[8];
  const float* wo_w  = (const float*)d_in[9];
  float* out = (float*)d_out;

  const int M = 16384, N = 1024, K = 1024;
  const size_t MN = (size_t)M * N;

  // ws: [r f32: 64 MiB][xi bf16: 32 MiB]  (96 MiB; proven available)
  float* r  = (float*)d_ws;
  bf16*  xi = (bf16*)((char*)d_ws + MN * 4);

  bf16* xb = nullptr, *wb = nullptr, *og = nullptr;
  hipGetSymbolAddress((void**)&xb, HIP_SYMBOL(g_xb));
  hipGetSymbolAddress((void**)&wb, HIP_SYMBOL(g_wb));
  hipGetSymbolAddress((void**)&og, HIP_SYMBOL(g_og));

  dim3 block(256);

  // 1) convert x and 5 weights to bf16
  conv_kernel<<<dim3(2048), block, 0, stream>>>(x, xb, (int)(MN / 4));
  const int W4 = 1024 * 1024 / 4;
  conv_kernel<<<dim3(256), block, 0, stream>>>(wr_w,  wb + 0 * 1024 * 1024, W4);
  conv_kernel<<<dim3(256), block, 0, stream>>>(wi_w,  wb + 1 * 1024 * 1024, W4);
  conv_kernel<<<dim3(256), block, 0, stream>>>(wig_w, wb + 2 * 1024 * 1024, W4);
  conv_kernel<<<dim3(256), block, 0, stream>>>(wog_w, wb + 3 * 1024 * 1024, W4);
  conv_kernel<<<dim3(256), block, 0, stream>>>(wo_w,  wb + 4 * 1024 * 1024, W4);

  // 2+3) all four projections in one pass (M-fastest grid)
  gemm_quad<<<dim3(64, 16), dim3(512), 0, stream>>>(
      xb,
      wb + 0 * 1024 * 1024,   // wr
      wb + 3 * 1024 * 1024,   // wog
      wb + 1 * 1024 * 1024,   // wi
      wb + 2 * 1024 * 1024,   // wig
      wr_b, wog_b, wig_b,
      r, og, xi, M, N, K);

  // 4) chunked scan; z in-place over xi; mem_out -> out tail (f32)
  scan_p1<<<dim3(1024), block, 0, stream>>>(r, xi);
  scan_p2<<<dim3(32),   block, 0, stream>>>(mem, out + MN);
  scan_p3<<<dim3(1024), block, 0, stream>>>(r, xi, og);

  // 5) y = z @ wo^T
  gemm_single<<<dim3(64, 8), dim3(512), 0, stream>>>(
      xi, wb + 4 * 1024 * 1024, out, M, N, K);
}

// Round 6
// 455.857 us; speedup vs baseline: 1.1184x; 1.0795x over previous
//
#include <hip/hip_runtime.h>
#include <hip/hip_bf16.h>
#include <cstdint>
#include <cstddef>

using bf16 = __hip_bfloat16;

typedef short s16x8 __attribute__((ext_vector_type(8)));
typedef short s16x4 __attribute__((ext_vector_type(4)));
typedef float f32x4 __attribute__((ext_vector_type(4)));

#define CH 32           // scan chunks
#define CS 64           // steps per chunk (CH*CS = 2048)

// ---- static device scratch (sidesteps unknown ws_size) -------------------
__device__ __align__(16) bf16  g_xb[16384 * 1024];      // 32 MiB: x in bf16
__device__ __align__(16) bf16  g_wb[5 * 1024 * 1024];   // 10 MiB: weights bf16
__device__ __align__(16) bf16  g_og[16384 * 1024];      // 32 MiB: output gate
__device__ float g_cA[CH * 8192];                       // scan carries / seeds
__device__ float g_cB[CH * 8192];

__device__ inline short bfbits(float f) {  // RNE f32 -> bf16 bits
  unsigned x = __float_as_uint(f);
  return (short)((x + 0x7FFFu + ((x >> 16) & 1u)) >> 16);
}
__device__ inline float sigmoidf_(float z) { return 1.0f / (1.0f + __expf(-z)); }

__device__ inline void gload_lds16(const void* g, void* l) {
  __builtin_amdgcn_global_load_lds(
      (const __attribute__((address_space(1))) void*)g,
      (__attribute__((address_space(3))) void*)l, 16, 0, 0);
}

// ---- f32 -> bf16 bulk convert (vec4, grid-stride) ------------------------
__global__ void conv_kernel(const float* __restrict__ src, bf16* __restrict__ dst, int n4) {
  int i = blockIdx.x * blockDim.x + threadIdx.x;
  const int stride = gridDim.x * blockDim.x;
  for (; i < n4; i += stride) {
    f32x4 v = ((const f32x4*)src)[i];
    s16x4 w;
    w[0] = bfbits(v[0]); w[1] = bfbits(v[1]);
    w[2] = bfbits(v[2]); w[3] = bfbits(v[3]);
    ((s16x4*)dst)[i] = w;
  }
}

// ===========================================================================
// QUAD GEMM v6: quad fusion x 2 blocks/CU (R3's sharing + R2's occupancy).
//   TM=128, TN=64, BK=32, 256 thr (4 waves). wave = (pair, row-half):
//   pair 0 waves -> {wr, wog} (r, og), pair 1 waves -> {wi, wig} (xi) —
//   gate pairs stay per-thread for the fused epilogue. Each wave: 64x64
//   output tile per mat of its pair -> acc 2x16 f32x4 = 128 regs,
//   32 MFMA/step.
//   LDS: flat tile [A 128x32 | B0..B3 64x32] = 24 KB, 3 buffers = 72 KB
//   -> 2 blocks/CU (144 KB). ~215 live regs < 256-cap at 2 waves/SIMD ->
//   no spill, 8 waves/CU with CROSS-BLOCK overlap (one block computes while
//   the other sits at its barrier - R2-proven mechanism, m114).
//   Schedule = R2's proven skeleton: stage(t+2); compute(t); vmcnt(6)
//   (= tile t+2's 6 loads stay in flight across the barrier); s_barrier.
//   Hazard: stage(t+2) overwrites buf[(t-1)%3], fully consumed before the
//   (t-1) barrier (ds_reads are consumed by MFMAs pre-barrier).
//   Swizzle for the 16-row x 4-chunk (64B row) shape:
//   c' = c ^ (row&3) ^ ((row>>2)&3) -> <=2-way (free; R4's c^(row&3) was
//   4-way: rows 4 apart collided). Pre-swizzled on the global source (LDS
//   dest stays linear for global_load_lds), XOR'd on the ds_read chunk;
//   row&3 == lane15&3 and (row>>2)&3 == (lane15>>2)&3 for every fragment
//   -> read-side XOR is one per-thread constant.
//   Grid M-fastest. K order: t*32 ascending == all prior rounds.
// ===========================================================================
__global__ __launch_bounds__(256, 2) void gemm_quad(
    const bf16* __restrict__ A,
    const bf16* __restrict__ B0, const bf16* __restrict__ B1,
    const bf16* __restrict__ B2, const bf16* __restrict__ B3,
    const float* __restrict__ bias_r, const float* __restrict__ bias_og,
    const float* __restrict__ bias_ig,
    float* __restrict__ Cr, bf16* __restrict__ Cog, bf16* __restrict__ Cxi,
    int M, int N, int K)
{
  __shared__ bf16 Ls[3][12288];   // [A 4096 | B0 2048 | B1 | B2 | B3] x3 buf

  const int tid  = threadIdx.x;
  const int wave = tid >> 6;      // 0..3
  const int lane = tid & 63;
  const int m0 = blockIdx.x * 128;   // M-fastest grid
  const int n0 = blockIdx.y * 64;
  const int pair = wave >> 1;     // 0: {wr,wog}, 1: {wi,wig}
  const int mh   = wave & 1;      // 64-row half

  // ---- staging: 1 instr = 64 lanes x 16B = 16 rows x 4 chunks ------------
  // tile-row = 16*a + (lane>>2): row&3 = (lane>>2)&3, (row>>2)&3 = (lane>>4)&3
  const int lrow = lane >> 2;                                            // 0..15
  const int schk = ((lane & 3) ^ ((lane >> 2) & 3) ^ ((lane >> 4) & 3)) << 3;
  // 24 x 1KB segments per tile; wave stages s = wave*6 + q (q=0..5)
  const bf16* ps[6];
  int lofs[6];
  #pragma unroll
  for (int q = 0; q < 6; ++q) {
    const int s = wave * 6 + q;
    const bf16* base;
    int rowbase;
    if (s < 8) { base = A; rowbase = m0 + s * 16; }          // A segs 0..7
    else {
      const int b = s - 8;                                   // B segs 0..15
      base = (b < 4) ? B0 : (b < 8) ? B1 : (b < 12) ? B2 : B3;
      rowbase = n0 + (b & 3) * 16;
    }
    ps[q]   = base + (size_t)(rowbase + lrow) * K + schk;
    lofs[q] = s * 512;
  }

  auto stage = [&](int b, int t) {
    const size_t koff = (size_t)t * 32;
    #pragma unroll
    for (int q = 0; q < 6; ++q)
      gload_lds16(ps[q] + koff, (void*)&Ls[b][lofs[q]]);
  };

  // ---- ds_read offsets (swizzled; XOR is a per-thread constant) ----------
  const int lane15 = lane & 15;
  const int csel   = lane >> 4;   // 0..3
  const int swzc   = ((csel ^ (lane15 & 3) ^ ((lane15 >> 2) & 3)) << 3);
  const int aBase  = (mh * 64 + lane15) * 32 + swzc;             // + i*512
  const int bBaseP = 4096 + pair * 4096 + lane15 * 32 + swzc;    // mat 2p; +2048 for 2p+1

  f32x4 accP[4][4] = {};   // mat 2*pair   (wr or wi)
  f32x4 accQ[4][4] = {};   // mat 2*pair+1 (wog or wig)

  auto compute = [&](int c) {
    const bf16* Lb = &Ls[c][0];
    s16x8 af[4], bP[4], bQ[4];
    #pragma unroll
    for (int i = 0; i < 4; ++i) af[i] = *(const s16x8*)(Lb + aBase + i * 512);
    #pragma unroll
    for (int j = 0; j < 4; ++j) {
      bP[j] = *(const s16x8*)(Lb + bBaseP + j * 512);
      bQ[j] = *(const s16x8*)(Lb + bBaseP + 2048 + j * 512);
    }
    __builtin_amdgcn_s_setprio(1);
    #pragma unroll
    for (int i = 0; i < 4; ++i)
      #pragma unroll
      for (int j = 0; j < 4; ++j) {
        accP[i][j] = __builtin_amdgcn_mfma_f32_16x16x32_bf16(af[i], bP[j], accP[i][j], 0, 0, 0);
        accQ[i][j] = __builtin_amdgcn_mfma_f32_16x16x32_bf16(af[i], bQ[j], accQ[i][j], 0, 0, 0);
      }
    __builtin_amdgcn_s_setprio(0);
  };

  // prologue: tiles 0,1 staged; wait oldest 6 (= tile 0)
  stage(0, 0);
  stage(1, 1);
  asm volatile("s_waitcnt vmcnt(6)" ::: "memory");
  __builtin_amdgcn_s_barrier();
  __builtin_amdgcn_sched_barrier(0);

  for (int t = 0; t < 30; ++t) {
    stage((t + 2) % 3, t + 2);
    __builtin_amdgcn_sched_barrier(0);   // stage issues stay ahead of compute
    compute(t % 3);
    // outstanding: tiles t+1, t+2 (12 loads); oldest 6 (t+1) must land
    asm volatile("s_waitcnt vmcnt(6)" ::: "memory");
    __builtin_amdgcn_s_barrier();
    __builtin_amdgcn_sched_barrier(0);
  }
  compute(0);                            // t=30
  asm volatile("s_waitcnt vmcnt(0)" ::: "memory");
  __builtin_amdgcn_s_barrier();
  __builtin_amdgcn_sched_barrier(0);
  compute(1);                            // t=31

  // ---- fused epilogue ----------------------------------------------------
  const int rq = (lane >> 4) * 4;
  const int cl = lane & 15;
  if (pair == 0) {
    #pragma unroll
    for (int j = 0; j < 4; ++j) {
      const int gc = n0 + j * 16 + cl;
      const float bR = bias_r[gc];
      const float bO = bias_og[gc];
      #pragma unroll
      for (int i = 0; i < 4; ++i) {
        const int gr = m0 + mh * 64 + i * 16 + rq;
        #pragma unroll
        for (int rr = 0; rr < 4; ++rr) {
          const size_t idx = (size_t)(gr + rr) * N + gc;
          Cr[idx]  = sigmoidf_(accP[i][j][rr] + bR);
          Cog[idx] = __float2bfloat16(sigmoidf_(accQ[i][j][rr] + bO));
        }
      }
    }
  } else {
    #pragma unroll
    for (int j = 0; j < 4; ++j) {
      const int gc = n0 + j * 16 + cl;
      const float bG = bias_ig[gc];
      #pragma unroll
      for (int i = 0; i < 4; ++i) {
        const int gr = m0 + mh * 64 + i * 16 + rq;
        #pragma unroll
        for (int rr = 0; rr < 4; ++rr) {
          const size_t idx = (size_t)(gr + rr) * N + gc;
          Cxi[idx] = __float2bfloat16(accP[i][j][rr] * sigmoidf_(accQ[i][j][rr] + bG));
        }
      }
    }
  }
}

// ===========================================================================
// gemm_single v6: y = z @ wo^T. Same skeleton at TM=128, TN=128, BK=32,
// 256 thr (4 waves; wave w = rows 0..127 x cols w*32..w*32+31, acc 64 regs).
// LDS: flat [A 128x32 | B 128x32] = 16 KB x3 buf = 48 KB; ~130 live regs
// -> (256,3): 3 blocks/CU. 4 loads/wave/tile -> in-loop vmcnt(4).
// ===========================================================================
__global__ __launch_bounds__(256, 3) void gemm_single(
    const bf16* __restrict__ A, const bf16* __restrict__ Bw,
    float* __restrict__ C, int M, int N, int K)
{
  __shared__ bf16 Ls[3][8192];   // [A 4096 | B 4096] x3

  const int tid  = threadIdx.x;
  const int wave = tid >> 6;     // 0..3
  const int lane = tid & 63;
  const int m0 = blockIdx.x * 128;   // M-fastest grid
  const int n0 = blockIdx.y * 128;

  const int lrow = lane >> 2;
  const int schk = ((lane & 3) ^ ((lane >> 2) & 3) ^ ((lane >> 4) & 3)) << 3;
  const bf16* ps[4];
  int lofs[4];
  #pragma unroll
  for (int q = 0; q < 4; ++q) {
    const int s = wave * 4 + q;
    const bf16* base = (s < 8) ? A : Bw;
    const int rowbase = (s < 8) ? (m0 + s * 16) : (n0 + (s - 8) * 16);
    ps[q]   = base + (size_t)(rowbase + lrow) * K + schk;
    lofs[q] = s * 512;
  }

  auto stage = [&](int b, int t) {
    const size_t koff = (size_t)t * 32;
    #pragma unroll
    for (int q = 0; q < 4; ++q)
      gload_lds16(ps[q] + koff, (void*)&Ls[b][lofs[q]]);
  };

  const int lane15 = lane & 15;
  const int csel   = lane >> 4;
  const int swzc   = ((csel ^ (lane15 & 3) ^ ((lane15 >> 2) & 3)) << 3);
  const int aBase  = lane15 * 32 + swzc;                            // + i*512
  const int bBase  = 4096 + (wave * 32 + lane15) * 32 + swzc;       // + j*512

  f32x4 acc[8][2] = {};

  auto compute = [&](int c) {
    const bf16* Lb = &Ls[c][0];
    s16x8 af[8], bfr[2];
    #pragma unroll
    for (int i = 0; i < 8; ++i) af[i] = *(const s16x8*)(Lb + aBase + i * 512);
    #pragma unroll
    for (int j = 0; j < 2; ++j) bfr[j] = *(const s16x8*)(Lb + bBase + j * 512);
    __builtin_amdgcn_s_setprio(1);
    #pragma unroll
    for (int i = 0; i < 8; ++i)
      #pragma unroll
      for (int j = 0; j < 2; ++j)
        acc[i][j] = __builtin_amdgcn_mfma_f32_16x16x32_bf16(af[i], bfr[j], acc[i][j], 0, 0, 0);
    __builtin_amdgcn_s_setprio(0);
  };

  stage(0, 0);
  stage(1, 1);
  asm volatile("s_waitcnt vmcnt(4)" ::: "memory");
  __builtin_amdgcn_s_barrier();
  __builtin_amdgcn_sched_barrier(0);

  for (int t = 0; t < 30; ++t) {
    stage((t + 2) % 3, t + 2);
    __builtin_amdgcn_sched_barrier(0);
    compute(t % 3);
    asm volatile("s_waitcnt vmcnt(4)" ::: "memory");
    __builtin_amdgcn_s_barrier();
    __builtin_amdgcn_sched_barrier(0);
  }
  compute(0);
  asm volatile("s_waitcnt vmcnt(0)" ::: "memory");
  __builtin_amdgcn_s_barrier();
  __builtin_amdgcn_sched_barrier(0);
  compute(1);

  const int rq = (lane >> 4) * 4;
  const int cl = lane & 15;
  #pragma unroll
  for (int j = 0; j < 2; ++j) {
    const int gc = n0 + wave * 32 + j * 16 + cl;
    #pragma unroll
    for (int i = 0; i < 8; ++i) {
      const int gr = m0 + i * 16 + rq;
      #pragma unroll
      for (int rr = 0; rr < 4; ++rr)
        C[(size_t)(gr + rr) * N + gc] = acc[i][j][rr];
    }
  }
}

// ---- chunked scan --------------------------------------------------------
__global__ __launch_bounds__(256) void scan_p1(
    const float* __restrict__ r, const bf16* __restrict__ xi)
{
  const int bid = blockIdx.x;                 // 0..1023
  const int c   = bid >> 5;                   // chunk
  const int idx = (bid & 31) * 256 + threadIdx.x;  // channel 0..8191
  const int b = idx >> 10, m = idx & 1023;
  const size_t base = ((size_t)b * 2048 + c * CS) * 1024 + m;
  float a = 1.0f, s = 0.0f;
  #pragma unroll 16
  for (int t = 0; t < CS; ++t) {
    const size_t o = base + (size_t)t * 1024;
    const float rv = r[o];
    const float xv = __bfloat162float(xi[o]);
    a *= rv;
    s = fmaf(s, rv, xv);
  }
  g_cA[c * 8192 + idx] = a;
  g_cB[c * 8192 + idx] = s;
}

__global__ __launch_bounds__(256) void scan_p2(
    const float* __restrict__ mem, float* __restrict__ memout)
{
  const int idx = blockIdx.x * 256 + threadIdx.x;  // 0..8191
  float H = mem[idx];
  #pragma unroll
  for (int c = 0; c < CH; ++c) {
    const float a = g_cA[c * 8192 + idx];
    const float s = g_cB[c * 8192 + idx];
    g_cA[c * 8192 + idx] = H;     // seed for chunk c
    H = fmaf(a, H, s);
  }
  memout[idx] = H;
}

__global__ __launch_bounds__(256) void scan_p3(
    const float* __restrict__ r, bf16* xi, const bf16* __restrict__ og)
{
  const int bid = blockIdx.x;
  const int c   = bid >> 5;
  const int idx = (bid & 31) * 256 + threadIdx.x;
  const int b = idx >> 10, m = idx & 1023;
  const size_t base = ((size_t)b * 2048 + c * CS) * 1024 + m;
  float h = g_cA[c * 8192 + idx];
  #pragma unroll 8
  for (int t = 0; t < CS; ++t) {
    const size_t o = base + (size_t)t * 1024;
    const float rv = r[o];
    const float xv = __bfloat162float(xi[o]);
    const float ov = __bfloat162float(og[o]);
    h = fmaf(h, rv, xv);
    xi[o] = __float2bfloat16(h / (1.0f + fabsf(h)) * ov);
  }
}

extern "C" void kernel_launch(void* const* d_in, const int* in_sizes, int n_in,
                              void* d_out, int out_size, void* d_ws, size_t ws_size,
                              hipStream_t stream)
{
  const float* x     = (const float*)d_in[0];
  const float* mem   = (const float*)d_in[1];
  const float* wr_w  = (const float*)d_in[2];
  const float* wr_b  = (const float*)d_in[3];
  const float* wi_w  = (const float*)d_in[4];
  const float* wig_w = (const float*)d_in[5];
  const float* wig_b = (const float*)d_in[6];
  const float* wog_w = (const float*)d_in[7];
  const float* wog_b = (const float*)d_in[8];
  const float* wo_w  = (const float*)d_in[9];
  float* out = (float*)d_out;

  const int M = 16384, N = 1024, K = 1024;
  const size_t MN = (size_t)M * N;

  // ws: [r f32: 64 MiB][xi bf16: 32 MiB]  (96 MiB; proven available)
  float* r  = (float*)d_ws;
  bf16*  xi = (bf16*)((char*)d_ws + MN * 4);

  bf16* xb = nullptr, *wb = nullptr, *og = nullptr;
  hipGetSymbolAddress((void**)&xb, HIP_SYMBOL(g_xb));
  hipGetSymbolAddress((void**)&wb, HIP_SYMBOL(g_wb));
  hipGetSymbolAddress((void**)&og, HIP_SYMBOL(g_og));

  dim3 block(256);

  // 1) convert x and 5 weights to bf16
  conv_kernel<<<dim3(2048), block, 0, stream>>>(x, xb, (int)(MN / 4));
  const int W4 = 1024 * 1024 / 4;
  conv_kernel<<<dim3(256), block, 0, stream>>>(wr_w,  wb + 0 * 1024 * 1024, W4);
  conv_kernel<<<dim3(256), block, 0, stream>>>(wi_w,  wb + 1 * 1024 * 1024, W4);
  conv_kernel<<<dim3(256), block, 0, stream>>>(wig_w, wb + 2 * 1024 * 1024, W4);
  conv_kernel<<<dim3(256), block, 0, stream>>>(wog_w, wb + 3 * 1024 * 1024, W4);
  conv_kernel<<<dim3(256), block, 0, stream>>>(wo_w,  wb + 4 * 1024 * 1024, W4);

  // 2+3) all four projections in one pass (M-fastest grid, 2 blocks/CU)
  gemm_quad<<<dim3(128, 16), block, 0, stream>>>(
      xb,
      wb + 0 * 1024 * 1024,   // wr
      wb + 3 * 1024 * 1024,   // wog
      wb + 1 * 1024 * 1024,   // wi
      wb + 2 * 1024 * 1024,   // wig
      wr_b, wog_b, wig_b,
      r, og, xi, M, N, K);

  // 4) chunked scan; z in-place over xi; mem_out -> out tail (f32)
  scan_p1<<<dim3(1024), block, 0, stream>>>(r, xi);
  scan_p2<<<dim3(32),   block, 0, stream>>>(mem, out + MN);
  scan_p3<<<dim3(1024), block, 0, stream>>>(r, xi, og);

  // 5) y = z @ wo^T
  gemm_single<<<dim3(128, 8), block, 0, stream>>>(
      xi, wb + 4 * 1024 * 1024, out, M, N, K);
}